// Round 4
// baseline (289.853 us; speedup 1.0000x reference)
//
#include <hip/hip_runtime.h>
#include <math.h>

#define BATCH 8
#define TENC 2048
#define TDEC 512
#define DIM 1024
#define NEG_BIG 1e20f

typedef __attribute__((ext_vector_type(8))) short short8;
typedef __attribute__((ext_vector_type(4))) float f32x4;
typedef unsigned short ushort_t;

// ---- fp32 -> bf16 helpers (round-to-nearest-even on raw bits) -------------
__device__ __forceinline__ unsigned int bf16rn(float x) {
    unsigned int u = __float_as_uint(x);
    return (u + 0x7FFFu + ((u >> 16) & 1u)) >> 16;
}
__device__ __forceinline__ float bf16f(unsigned int b) {
    return __uint_as_float(b << 16);
}
__device__ __forceinline__ void split2(float x, unsigned int& h, unsigned int& l) {
    h = bf16rn(x);
    l = bf16rn(x - bf16f(h));
}

// async global(bf16 data) -> LDS, 16B per lane, wave-uniform LDS base
#define GLOAD16(g, l)                                                        \
    __builtin_amdgcn_global_load_lds(                                        \
        (const __attribute__((address_space(1))) unsigned int*)(g),          \
        (__attribute__((address_space(3))) unsigned int*)(l), 16, 0, 0)

// ===========================================================================
// PRIMARY PATH (needs ~128.2 MiB workspace)
// ===========================================================================

// ---------------------------------------------------------------------------
// prep_enc: enc fp32 [b][t][d] -> encH/encL bf16 [b][t][d] + encT bf16 [b][d][t]
// ---------------------------------------------------------------------------
__global__ __launch_bounds__(256) void prep_enc(
    const float* __restrict__ enc, ushort_t* __restrict__ encH,
    ushort_t* __restrict__ encL, ushort_t* __restrict__ encT)
{
    __shared__ ushort_t T[64][72];

    const int b  = blockIdx.z;
    const int t0 = blockIdx.y * 64;
    const int d0 = blockIdx.x * 64;
    const int tid = threadIdx.x;

    const int tr = tid >> 4;
    const int dc = (tid & 15) * 4;

    const float* E = enc + (size_t)b * TENC * DIM;

#pragma unroll
    for (int i = 0; i < 4; ++i) {
        const int t = t0 + tr + 16 * i;
        float4 x = *(const float4*)&E[(size_t)t * DIM + d0 + dc];
        float xs[4] = {x.x, x.y, x.z, x.w};
        unsigned int h[4], l[4];
#pragma unroll
        for (int j = 0; j < 4; ++j) split2(xs[j], h[j], l[j]);
        ushort_t* ph = &encH[((size_t)b * TENC + t) * DIM + d0 + dc];
        ushort_t* pl = &encL[((size_t)b * TENC + t) * DIM + d0 + dc];
        *(uint2*)ph = make_uint2(h[0] | (h[1] << 16), h[2] | (h[3] << 16));
        *(uint2*)pl = make_uint2(l[0] | (l[1] << 16), l[2] | (l[3] << 16));
        const int tloc = tr + 16 * i;
#pragma unroll
        for (int j = 0; j < 4; ++j) T[dc + j][tloc] = (ushort_t)h[j];
    }
    __syncthreads();

    const int dr = tid >> 2;
    const int tc = (tid & 3) * 16;
    short8 v0 = *(const short8*)&T[dr][tc];
    short8 v1 = *(const short8*)&T[dr][tc + 8];
    ushort_t* out = &encT[((size_t)b * DIM + d0 + dr) * TENC + t0 + tc];
    *(short8*)out = v0;
    *(short8*)(out + 8) = v1;
}

// ---------------------------------------------------------------------------
__global__ __launch_bounds__(256) void prep_dec(
    const float* __restrict__ dec, ushort_t* __restrict__ decH,
    ushort_t* __restrict__ decL)
{
    const size_t i4 = (size_t)blockIdx.x * 256 + threadIdx.x;
    float4 x = *(const float4*)(dec + i4 * 4);
    float xs[4] = {x.x, x.y, x.z, x.w};
    unsigned int h[4], l[4];
#pragma unroll
    for (int j = 0; j < 4; ++j) split2(xs[j], h[j], l[j]);
    *(uint2*)(decH + i4 * 4) = make_uint2(h[0] | (h[1] << 16), h[2] | (h[3] << 16));
    *(uint2*)(decL + i4 * 4) = make_uint2(l[0] | (l[1] << 16), l[2] | (l[3] << 16));
}

__global__ __launch_bounds__(256) void zero_ctx(float* __restrict__ ctx)
{
    const size_t i4 = (size_t)blockIdx.x * 256 + threadIdx.x;
    *(float4*)(ctx + i4 * 4) = make_float4(0.f, 0.f, 0.f, 0.f);
}

// ---------------------------------------------------------------------------
// gemm1_lds: raw[b,t,u] = enc·dec (split-bf16) - mask, m97 structure with
// XOR-swizzled LDS k-chunks (bank-conflict-free fragment reads) and a fused
// per-column (max, sum-exp) partial-stat epilogue -> pm/ps[16][B*TDEC].
// ---------------------------------------------------------------------------
__global__ __launch_bounds__(256) void gemm1_lds(
    const ushort_t* __restrict__ encH, const ushort_t* __restrict__ encL,
    const ushort_t* __restrict__ decH, const ushort_t* __restrict__ decL,
    const int* __restrict__ mask, float* __restrict__ raw,
    float* __restrict__ pm, float* __restrict__ ps)
{
    __shared__ __align__(16) ushort_t Ah[128 * 32];
    __shared__ __align__(16) ushort_t Al[128 * 32];
    __shared__ __align__(16) ushort_t Bh[128 * 32];
    __shared__ __align__(16) ushort_t Bl[128 * 32];
    __shared__ float smx[4][68];
    __shared__ float ssx[4][68];

    const int b  = blockIdx.z;
    const int m0 = blockIdx.y * 128;   // t
    const int n0 = blockIdx.x * 128;   // u
    const int tid = threadIdx.x;

    const int lane = tid & 63;
    const int w    = tid >> 6;
    const int wm   = (w & 1) * 64;
    const int wn   = (w >> 1) * 64;
    const int lr   = lane & 15;
    const int q    = lane >> 4;

    // staging: lane L lands at LDS row (L>>2), chunk (L&3); global chunk is
    // XOR-swizzled so that phys chunk p holds logical chunk p ^ s(row)
    const int srow  = lane >> 2;
    const int sswz  = (srow + (srow >> 2)) & 3;
    const int scol  = (((lane & 3) ^ sswz)) * 8;   // global offset (shorts)

    // fragment reads: logical chunk q lives at phys chunk q ^ s(lr)
    const int qs = (q ^ ((lr + (lr >> 2)) & 3)) * 8;

    const ushort_t* AH = encH + (size_t)b * TENC * DIM;
    const ushort_t* AL = encL + (size_t)b * TENC * DIM;
    const ushort_t* BH = decH + (size_t)b * TDEC * DIM;
    const ushort_t* BL = decL + (size_t)b * TDEC * DIM;
    float* C = raw + (size_t)b * TENC * TDEC;

    f32x4 acc[4][4] = {};

    for (int k0 = 0; k0 < DIM; k0 += 32) {
        __syncthreads();
#pragma unroll
        for (int q2 = 0; q2 < 2; ++q2) {
            const int rg  = w * 2 + q2;
            const int row = rg * 16 + srow;
            const size_t ga = (size_t)(m0 + row) * DIM + k0 + scol;
            const size_t gb = (size_t)(n0 + row) * DIM + k0 + scol;
            GLOAD16(AH + ga, &Ah[rg * 16 * 32]);
            GLOAD16(AL + ga, &Al[rg * 16 * 32]);
            GLOAD16(BH + gb, &Bh[rg * 16 * 32]);
            GLOAD16(BL + gb, &Bl[rg * 16 * 32]);
        }
        __syncthreads();

        short8 ah[4], al[4], bh[4], bl[4];
#pragma unroll
        for (int i = 0; i < 4; ++i) {
            ah[i] = *(const short8*)&Ah[(wm + i * 16 + lr) * 32 + qs];
            al[i] = *(const short8*)&Al[(wm + i * 16 + lr) * 32 + qs];
            bh[i] = *(const short8*)&Bh[(wn + i * 16 + lr) * 32 + qs];
            bl[i] = *(const short8*)&Bl[(wn + i * 16 + lr) * 32 + qs];
        }
#pragma unroll
        for (int i = 0; i < 4; ++i)
#pragma unroll
            for (int j = 0; j < 4; ++j) {
                acc[i][j] = __builtin_amdgcn_mfma_f32_16x16x32_bf16(ah[i], bh[j], acc[i][j], 0, 0, 0);
                acc[i][j] = __builtin_amdgcn_mfma_f32_16x16x32_bf16(ah[i], bl[j], acc[i][j], 0, 0, 0);
                acc[i][j] = __builtin_amdgcn_mfma_f32_16x16x32_bf16(al[i], bh[j], acc[i][j], 0, 0, 0);
            }
    }

    // masks per row held by this lane
    float mkv[4][4];
#pragma unroll
    for (int i = 0; i < 4; ++i)
#pragma unroll
        for (int rr = 0; rr < 4; ++rr) {
            const int t = m0 + wm + i * 16 + q * 4 + rr;
            mkv[i][rr] = (mask[b * TENC + t] == 0) ? NEG_BIG : 0.0f;
        }

    // pass 1: store C (C/D layout col=lane&15, row=quad*4+reg) + column max
    float cm[4] = {-INFINITY, -INFINITY, -INFINITY, -INFINITY};
    float cs[4] = {0.f, 0.f, 0.f, 0.f};
#pragma unroll
    for (int i = 0; i < 4; ++i)
#pragma unroll
        for (int rr = 0; rr < 4; ++rr) {
            const int t = m0 + wm + i * 16 + q * 4 + rr;
#pragma unroll
            for (int j = 0; j < 4; ++j) {
                const int u = n0 + wn + j * 16 + lr;
                const float v = acc[i][j][rr] - mkv[i][rr];
                C[(size_t)t * TDEC + u] = v;
                cm[j] = fmaxf(cm[j], v);
            }
        }
    // pass 2: column sum of exp
#pragma unroll
    for (int i = 0; i < 4; ++i)
#pragma unroll
        for (int rr = 0; rr < 4; ++rr)
#pragma unroll
            for (int j = 0; j < 4; ++j)
                cs[j] += __expf(acc[i][j][rr] - mkv[i][rr] - cm[j]);

    // combine across the 4 q-groups (lanes lr, lr+16, lr+32, lr+48)
#pragma unroll
    for (int j = 0; j < 4; ++j) {
#pragma unroll
        for (int d = 16; d < 64; d <<= 1) {
            float om = __shfl_xor(cm[j], d, 64);
            float os = __shfl_xor(cs[j], d, 64);
            float mn = fmaxf(cm[j], om);
            cs[j] = cs[j] * __expf(cm[j] - mn) + os * __expf(om - mn);
            cm[j] = mn;
        }
    }

    // combine the two waves covering the same 64 columns (wm=0 and wm=64)
    if (q == 0) {
#pragma unroll
        for (int j = 0; j < 4; ++j) {
            smx[w][j * 16 + lr] = cm[j];
            ssx[w][j * 16 + lr] = cs[j];
        }
    }
    __syncthreads();
    if (tid < 128) {
        const int col = tid;               // 0..127 within block tile
        const int wp  = (col >> 6) * 2;    // wave pair for this column half
        const int ci  = col & 63;
        const float m1 = smx[wp][ci],     s1 = ssx[wp][ci];
        const float m2 = smx[wp + 1][ci], s2 = ssx[wp + 1][ci];
        const float M = fmaxf(m1, m2);
        const float S = s1 * __expf(m1 - M) + s2 * __expf(m2 - M);
        const int idx = b * TDEC + n0 + col;
        const int tb  = m0 >> 7;           // 0..15
        pm[(size_t)tb * (BATCH * TDEC) + idx] = M;
        ps[(size_t)tb * (BATCH * TDEC) + idx] = S;
    }
}

// ---------------------------------------------------------------------------
// colstat2: combine 16 per-t-block partials -> colM, colI. 4096 columns.
// ---------------------------------------------------------------------------
__global__ __launch_bounds__(256) void colstat2(
    const float* __restrict__ pm, const float* __restrict__ ps,
    float* __restrict__ colM, float* __restrict__ colI)
{
    const int idx = blockIdx.x * 256 + threadIdx.x;
    float M = -INFINITY;
#pragma unroll
    for (int z = 0; z < 16; ++z)
        M = fmaxf(M, pm[(size_t)z * (BATCH * TDEC) + idx]);
    float s = 0.0f;
#pragma unroll
    for (int z = 0; z < 16; ++z)
        s += ps[(size_t)z * (BATCH * TDEC) + idx] *
             __expf(pm[(size_t)z * (BATCH * TDEC) + idx] - M);
    colM[idx] = M;
    colI[idx] = 1.0f / s;
}

// ---------------------------------------------------------------------------
// norm: scores = exp(raw-M)*inv in place (fp32) + scoresT bf16 [u][t].
// ---------------------------------------------------------------------------
__global__ __launch_bounds__(256) void norm_kernel(
    float* __restrict__ S, const float* __restrict__ colM,
    const float* __restrict__ colI, ushort_t* __restrict__ scoresT)
{
    __shared__ ushort_t T[64][72];

    const int b  = blockIdx.z;
    const int t0 = blockIdx.x * 64;
    const int u0 = blockIdx.y * 64;
    const int tid = threadIdx.x;

    const int tr  = tid >> 4;
    const int ucl = (tid & 15) * 4;

    float4 M4 = *(const float4*)&colM[b * TDEC + u0 + ucl];
    float4 I4 = *(const float4*)&colI[b * TDEC + u0 + ucl];

    float* base = S + (size_t)b * TENC * TDEC;

#pragma unroll
    for (int i = 0; i < 4; ++i) {
        const int t = t0 + tr + 16 * i;
        float4 x = *(const float4*)&base[(size_t)t * TDEC + u0 + ucl];
        float4 p;
        p.x = __expf(x.x - M4.x) * I4.x;
        p.y = __expf(x.y - M4.y) * I4.y;
        p.z = __expf(x.z - M4.z) * I4.z;
        p.w = __expf(x.w - M4.w) * I4.w;
        *(float4*)&base[(size_t)t * TDEC + u0 + ucl] = p;
        const int tloc = tr + 16 * i;
        T[ucl + 0][tloc] = (ushort_t)bf16rn(p.x);
        T[ucl + 1][tloc] = (ushort_t)bf16rn(p.y);
        T[ucl + 2][tloc] = (ushort_t)bf16rn(p.z);
        T[ucl + 3][tloc] = (ushort_t)bf16rn(p.w);
    }
    __syncthreads();

    const int ur = tid >> 2;
    const int tc = (tid & 3) * 16;
    short8 v0 = *(const short8*)&T[ur][tc];
    short8 v1 = *(const short8*)&T[ur][tc + 8];
    ushort_t* out = &scoresT[((size_t)b * TDEC + u0 + ur) * TENC + t0 + tc];
    *(short8*)out = v0;
    *(short8*)(out + 8) = v1;
}

// ---------------------------------------------------------------------------
// gemm2_lds: context[b,u,d] += sum_t scoresT[b,u,t]*encT[b,d,t]  (bf16 single)
// 128x128 tile, BK=32, split-K=4 + atomicAdd. Grid (8, 4, 32). Swizzled LDS.
// ---------------------------------------------------------------------------
__global__ __launch_bounds__(256) void gemm2_lds(
    const ushort_t* __restrict__ scoresT, const ushort_t* __restrict__ encT,
    float* __restrict__ context)
{
    __shared__ __align__(16) ushort_t Ah[128 * 32];
    __shared__ __align__(16) ushort_t Bh[128 * 32];

    const int b  = blockIdx.z >> 2;
    const int ks = blockIdx.z & 3;
    const int m0 = blockIdx.y * 128;   // u
    const int n0 = blockIdx.x * 128;   // d
    const int tid = threadIdx.x;

    const int lane = tid & 63;
    const int w    = tid >> 6;
    const int wm   = (w & 1) * 64;
    const int wn   = (w >> 1) * 64;
    const int lr   = lane & 15;
    const int q    = lane >> 4;

    const int srow = lane >> 2;
    const int sswz = (srow + (srow >> 2)) & 3;
    const int scol = (((lane & 3) ^ sswz)) * 8;
    const int qs   = (q ^ ((lr + (lr >> 2)) & 3)) * 8;

    const ushort_t* A = scoresT + (size_t)b * TDEC * TENC;
    const ushort_t* B = encT    + (size_t)b * DIM * TENC;
    float* C = context + (size_t)b * TDEC * DIM;

    const int kbeg = ks * (TENC / 4);
    const int kend = kbeg + TENC / 4;

    f32x4 acc[4][4] = {};

    for (int k0 = kbeg; k0 < kend; k0 += 32) {
        __syncthreads();
#pragma unroll
        for (int q2 = 0; q2 < 2; ++q2) {
            const int rg  = w * 2 + q2;
            const int row = rg * 16 + srow;
            GLOAD16(A + (size_t)(m0 + row) * TENC + k0 + scol, &Ah[rg * 16 * 32]);
            GLOAD16(B + (size_t)(n0 + row) * TENC + k0 + scol, &Bh[rg * 16 * 32]);
        }
        __syncthreads();

        short8 ah[4], bh[4];
#pragma unroll
        for (int i = 0; i < 4; ++i) {
            ah[i] = *(const short8*)&Ah[(wm + i * 16 + lr) * 32 + qs];
            bh[i] = *(const short8*)&Bh[(wn + i * 16 + lr) * 32 + qs];
        }
#pragma unroll
        for (int i = 0; i < 4; ++i)
#pragma unroll
            for (int j = 0; j < 4; ++j)
                acc[i][j] = __builtin_amdgcn_mfma_f32_16x16x32_bf16(ah[i], bh[j], acc[i][j], 0, 0, 0);
    }

#pragma unroll
    for (int i = 0; i < 4; ++i)
#pragma unroll
        for (int rr = 0; rr < 4; ++rr) {
            const int u = m0 + wm + i * 16 + q * 4 + rr;
#pragma unroll
            for (int j = 0; j < 4; ++j) {
                const int d = n0 + wn + j * 16 + lr;
                atomicAdd(&C[(size_t)u * DIM + d], acc[i][j][rr]);
            }
        }
}

// ===========================================================================
// FALLBACK PATH (round-2 proven kernels; used if workspace is too small)
// ===========================================================================

__device__ __forceinline__ void store8(ushort_t* ph, ushort_t* pl,
                                       float4 x0, float4 x1) {
    float xs[8] = {x0.x, x0.y, x0.z, x0.w, x1.x, x1.y, x1.z, x1.w};
    short8 hv, lv;
#pragma unroll
    for (int i = 0; i < 8; ++i) {
        unsigned int h, l;
        split2(xs[i], h, l);
        hv[i] = (short)h;
        lv[i] = (short)l;
    }
    *(short8*)ph = hv;
    *(short8*)pl = lv;
}

__device__ __forceinline__ void wr4(ushort_t* ph, ushort_t* pl, const float* x) {
    unsigned int h[4], l[4];
#pragma unroll
    for (int i = 0; i < 4; ++i) split2(x[i], h[i], l[i]);
    *(uint2*)ph = make_uint2(h[0] | (h[1] << 16), h[2] | (h[3] << 16));
    *(uint2*)pl = make_uint2(l[0] | (l[1] << 16), l[2] | (l[3] << 16));
}

__device__ __forceinline__ short8 frag8B(const ushort_t* p) {
    union { short8 v; uint2 u[2]; } f;
    f.u[0] = *(const uint2*)p;
    f.u[1] = *(const uint2*)(p + 4);
    return f.v;
}

__global__ __launch_bounds__(256) void gemm1_mfma(
    const float* __restrict__ enc, const float* __restrict__ dec,
    const int* __restrict__ mask, float* __restrict__ raw)
{
    __shared__ __align__(16) ushort_t Ah[128 * 32];
    __shared__ __align__(16) ushort_t Al[128 * 32];
    __shared__ __align__(16) ushort_t Bh[128 * 32];
    __shared__ __align__(16) ushort_t Bl[128 * 32];

    const int b  = blockIdx.z;
    const int m0 = blockIdx.y * 128;
    const int n0 = blockIdx.x * 128;
    const int tid = threadIdx.x;

    const float* A  = enc + (size_t)b * TENC * DIM;
    const float* Bg = dec + (size_t)b * TDEC * DIM;
    float*       C  = raw + (size_t)b * TENC * TDEC;

    const int lane = tid & 63;
    const int wv   = tid >> 6;
    const int wm   = (wv & 1) * 64;
    const int wn   = (wv >> 1) * 64;
    const int lr   = lane & 15;
    const int q    = lane >> 4;

    const int r0 = tid >> 2;
    const int c8 = (tid & 3) * 8;

    f32x4 acc[4][4] = {};

    for (int k0 = 0; k0 < DIM; k0 += 32) {
        const float* pa0 = A  + (size_t)(m0 + r0) * DIM + k0 + c8;
        const float* pa1 = A  + (size_t)(m0 + r0 + 64) * DIM + k0 + c8;
        const float* pb0 = Bg + (size_t)(n0 + r0) * DIM + k0 + c8;
        const float* pb1 = Bg + (size_t)(n0 + r0 + 64) * DIM + k0 + c8;
        float4 a0 = *(const float4*)pa0, a0b = *(const float4*)(pa0 + 4);
        float4 a1 = *(const float4*)pa1, a1b = *(const float4*)(pa1 + 4);
        float4 b0 = *(const float4*)pb0, b0b = *(const float4*)(pb0 + 4);
        float4 b1 = *(const float4*)pb1, b1b = *(const float4*)(pb1 + 4);

        __syncthreads();
        store8(&Ah[r0 * 32 + c8],        &Al[r0 * 32 + c8],        a0, a0b);
        store8(&Ah[(r0 + 64) * 32 + c8], &Al[(r0 + 64) * 32 + c8], a1, a1b);
        store8(&Bh[r0 * 32 + c8],        &Bl[r0 * 32 + c8],        b0, b0b);
        store8(&Bh[(r0 + 64) * 32 + c8], &Bl[(r0 + 64) * 32 + c8], b1, b1b);
        __syncthreads();

        short8 ah[4], al[4], bh[4], bl[4];
#pragma unroll
        for (int i = 0; i < 4; ++i) {
            ah[i] = *(const short8*)&Ah[(wm + i * 16 + lr) * 32 + q * 8];
            al[i] = *(const short8*)&Al[(wm + i * 16 + lr) * 32 + q * 8];
            bh[i] = *(const short8*)&Bh[(wn + i * 16 + lr) * 32 + q * 8];
            bl[i] = *(const short8*)&Bl[(wn + i * 16 + lr) * 32 + q * 8];
        }
#pragma unroll
        for (int i = 0; i < 4; ++i)
#pragma unroll
            for (int j = 0; j < 4; ++j) {
                acc[i][j] = __builtin_amdgcn_mfma_f32_16x16x32_bf16(ah[i], bh[j], acc[i][j], 0, 0, 0);
                acc[i][j] = __builtin_amdgcn_mfma_f32_16x16x32_bf16(ah[i], bl[j], acc[i][j], 0, 0, 0);
                acc[i][j] = __builtin_amdgcn_mfma_f32_16x16x32_bf16(al[i], bh[j], acc[i][j], 0, 0, 0);
            }
    }

#pragma unroll
    for (int i = 0; i < 4; ++i)
#pragma unroll
        for (int rr = 0; rr < 4; ++rr) {
            const int t = m0 + wm + i * 16 + q * 4 + rr;
            const float mk = (mask[b * TENC + t] == 0) ? NEG_BIG : 0.0f;
#pragma unroll
            for (int j = 0; j < 4; ++j) {
                const int u = n0 + wn + j * 16 + lr;
                C[(size_t)t * TDEC + u] = acc[i][j][rr] - mk;
            }
        }
}

__global__ __launch_bounds__(256) void softmax_kernel(float* __restrict__ S)
{
    const int b  = blockIdx.y;
    const int u0 = blockIdx.x * 16;
    const int up = threadIdx.x & 15;
    const int tg = threadIdx.x >> 4;

    float* col = S + (size_t)b * TENC * TDEC + u0;

    float m = -INFINITY, s = 0.0f;
    for (int t = tg; t < TENC; t += 16) {
        float x = col[(size_t)t * TDEC + up];
        float mn = fmaxf(m, x);
        s = s * __expf(m - mn) + __expf(x - mn);
        m = mn;
    }

    __shared__ float sm[16][17];
    __shared__ float ss[16][17];
    sm[tg][up] = m;
    ss[tg][up] = s;
    __syncthreads();

    float M = -INFINITY;
#pragma unroll
    for (int j = 0; j < 16; ++j) M = fmaxf(M, sm[j][up]);
    float sum = 0.0f;
#pragma unroll
    for (int j = 0; j < 16; ++j) sum += ss[j][up] * __expf(sm[j][up] - M);
    const float inv = 1.0f / sum;

    for (int t = tg; t < TENC; t += 16) {
        float x = col[(size_t)t * TDEC + up];
        col[(size_t)t * TDEC + up] = __expf(x - M) * inv;
    }
}

#define G2_LD 36

__global__ __launch_bounds__(256) void gemm2_mfma(
    const float* __restrict__ scores, const float* __restrict__ enc,
    float* __restrict__ context)
{
    __shared__ __align__(16) ushort_t Ah[128 * G2_LD];
    __shared__ __align__(16) ushort_t Al[128 * G2_LD];
    __shared__ __align__(16) ushort_t Bh[128 * G2_LD];
    __shared__ __align__(16) ushort_t Bl[128 * G2_LD];

    const int b  = blockIdx.z;
    const int m0 = blockIdx.y * 128;
    const int n0 = blockIdx.x * 128;
    const int tid = threadIdx.x;

    const float* S = scores + (size_t)b * TENC * TDEC;
    const float* E = enc    + (size_t)b * TENC * DIM;
    float*       C = context + (size_t)b * TDEC * DIM;

    const int lane = tid & 63;
    const int wv   = tid >> 6;
    const int wm   = (wv & 1) * 64;
    const int wn   = (wv >> 1) * 64;
    const int lr   = lane & 15;
    const int q    = lane >> 4;

    const int ul = tid & 127;
    const int th = (tid >> 7) * 16;

    f32x4 acc[4][4] = {};

    for (int k0 = 0; k0 < TENC; k0 += 32) {
        float av[16], bv[16];
#pragma unroll
        for (int i = 0; i < 4; ++i) {
            const int t = k0 + th + i * 4;
#pragma unroll
            for (int j = 0; j < 4; ++j) {
                av[i * 4 + j] = S[(size_t)(t + j) * TDEC + m0 + ul];
                bv[i * 4 + j] = E[(size_t)(t + j) * DIM + n0 + ul];
            }
        }
        __syncthreads();
#pragma unroll
        for (int i = 0; i < 4; ++i) {
            const int tt = th + i * 4;
            wr4(&Ah[ul * G2_LD + tt], &Al[ul * G2_LD + tt], &av[i * 4]);
            wr4(&Bh[ul * G2_LD + tt], &Bl[ul * G2_LD + tt], &bv[i * 4]);
        }
        __syncthreads();

        short8 ah[4], al[4], bh[4], bl[4];
#pragma unroll
        for (int i = 0; i < 4; ++i) {
            ah[i] = frag8B(&Ah[(wm + i * 16 + lr) * G2_LD + q * 8]);
            al[i] = frag8B(&Al[(wm + i * 16 + lr) * G2_LD + q * 8]);
            bh[i] = frag8B(&Bh[(wn + i * 16 + lr) * G2_LD + q * 8]);
            bl[i] = frag8B(&Bl[(wn + i * 16 + lr) * G2_LD + q * 8]);
        }
#pragma unroll
        for (int i = 0; i < 4; ++i)
#pragma unroll
            for (int j = 0; j < 4; ++j) {
                acc[i][j] = __builtin_amdgcn_mfma_f32_16x16x32_bf16(ah[i], bh[j], acc[i][j], 0, 0, 0);
                acc[i][j] = __builtin_amdgcn_mfma_f32_16x16x32_bf16(ah[i], bl[j], acc[i][j], 0, 0, 0);
                acc[i][j] = __builtin_amdgcn_mfma_f32_16x16x32_bf16(al[i], bh[j], acc[i][j], 0, 0, 0);
            }
    }

#pragma unroll
    for (int i = 0; i < 4; ++i)
#pragma unroll
        for (int rr = 0; rr < 4; ++rr) {
            const int u = m0 + wm + i * 16 + q * 4 + rr;
#pragma unroll
            for (int j = 0; j < 4; ++j) {
                const int d = n0 + wn + j * 16 + lr;
                C[(size_t)u * DIM + d] = acc[i][j][rr];
            }
        }
}

// ===========================================================================
extern "C" void kernel_launch(void* const* d_in, const int* in_sizes, int n_in,
                              void* d_out, int out_size, void* d_ws, size_t ws_size,
                              hipStream_t stream)
{
    const float* enc      = (const float*)d_in[0];
    const int*   enc_mask = (const int*)  d_in[1];
    const float* dec      = (const float*)d_in[2];

    float* context = (float*)d_out;                        // B*TDEC*DIM
    float* scores  = context + (size_t)BATCH * TDEC * DIM; // B*TENC*TDEC

    // workspace layout (bytes). pm/ps overlay the scoresT region: they are
    // fully consumed by colstat2 before norm_kernel writes scoresT.
    const size_t OFF_ENC_H = 0;
    const size_t OFF_ENC_L = 33554432;
    const size_t OFF_DEC_H = 67108864;
    const size_t OFF_DEC_L = 75497472;
    const size_t OFF_ENC_T = 83886080;
    const size_t OFF_SCO_T = 117440512;
    const size_t OFF_PM    = OFF_SCO_T;            // 16*4096 floats = 256 KB
    const size_t OFF_PS    = OFF_SCO_T + 262144;   // 256 KB
    const size_t OFF_COL_M = 134217728;
    const size_t OFF_COL_I = 134234112;
    const size_t WS_NEED   = 134381568;

    if (ws_size >= WS_NEED) {
        char* w = (char*)d_ws;
        ushort_t* encH    = (ushort_t*)(w + OFF_ENC_H);
        ushort_t* encL    = (ushort_t*)(w + OFF_ENC_L);
        ushort_t* decH    = (ushort_t*)(w + OFF_DEC_H);
        ushort_t* decL    = (ushort_t*)(w + OFF_DEC_L);
        ushort_t* encT    = (ushort_t*)(w + OFF_ENC_T);
        ushort_t* scoresT = (ushort_t*)(w + OFF_SCO_T);
        float*    pm      = (float*)(w + OFF_PM);
        float*    ps      = (float*)(w + OFF_PS);
        float*    colM    = (float*)(w + OFF_COL_M);
        float*    colI    = (float*)(w + OFF_COL_I);

        prep_enc<<<dim3(DIM / 64, TENC / 64, BATCH), 256, 0, stream>>>(
            enc, encH, encL, encT);
        prep_dec<<<4096, 256, 0, stream>>>(dec, decH, decL);
        zero_ctx<<<4096, 256, 0, stream>>>(context);

        gemm1_lds<<<dim3(TDEC / 128, TENC / 128, BATCH), 256, 0, stream>>>(
            encH, encL, decH, decL, enc_mask, scores, pm, ps);

        colstat2<<<16, 256, 0, stream>>>(pm, ps, colM, colI);

        norm_kernel<<<dim3(TENC / 64, TDEC / 64, BATCH), 256, 0, stream>>>(
            scores, colM, colI, scoresT);

        gemm2_lds<<<dim3(DIM / 128, TDEC / 128, BATCH * 4), 256, 0, stream>>>(
            scoresT, encT, context);
    } else {
        gemm1_mfma<<<dim3(TDEC / 128, TENC / 128, BATCH), 256, 0, stream>>>(
            enc, dec, enc_mask, scores);
        softmax_kernel<<<dim3(TDEC / 16, BATCH), 256, 0, stream>>>(scores);
        gemm2_mfma<<<dim3(DIM / 128, TDEC / 128, BATCH), 256, 0, stream>>>(
            scores, enc, context);
    }
}

// Round 5
// 271.468 us; speedup vs baseline: 1.0677x; 1.0677x over previous
//
#include <hip/hip_runtime.h>
#include <math.h>

#define BATCH 8
#define TENC 2048
#define TDEC 512
#define DIM 1024
#define NEG_BIG 1e20f

typedef __attribute__((ext_vector_type(8))) short short8;
typedef __attribute__((ext_vector_type(4))) float f32x4;
typedef unsigned short ushort_t;

// ---- fp32 -> bf16 helpers (round-to-nearest-even on raw bits) -------------
__device__ __forceinline__ unsigned int bf16rn(float x) {
    unsigned int u = __float_as_uint(x);
    return (u + 0x7FFFu + ((u >> 16) & 1u)) >> 16;
}
__device__ __forceinline__ float bf16f(unsigned int b) {
    return __uint_as_float(b << 16);
}
__device__ __forceinline__ void split2(float x, unsigned int& h, unsigned int& l) {
    h = bf16rn(x);
    l = bf16rn(x - bf16f(h));
}

// async global(bf16 data) -> LDS, 16B per lane, wave-uniform LDS base
#define GLOAD16(g, l)                                                        \
    __builtin_amdgcn_global_load_lds(                                        \
        (const __attribute__((address_space(1))) unsigned int*)(g),          \
        (__attribute__((address_space(3))) unsigned int*)(l), 16, 0, 0)

// ===========================================================================
// PRIMARY PATH (needs ~128.2 MiB workspace)
// ===========================================================================

// ---------------------------------------------------------------------------
// prep_enc: enc fp32 [b][t][d] -> encH/encL bf16 [b][t][d] + encT bf16 [b][d][t]
// ---------------------------------------------------------------------------
__global__ __launch_bounds__(256) void prep_enc(
    const float* __restrict__ enc, ushort_t* __restrict__ encH,
    ushort_t* __restrict__ encL, ushort_t* __restrict__ encT)
{
    __shared__ ushort_t T[64][72];

    const int b  = blockIdx.z;
    const int t0 = blockIdx.y * 64;
    const int d0 = blockIdx.x * 64;
    const int tid = threadIdx.x;

    const int tr = tid >> 4;
    const int dc = (tid & 15) * 4;

    const float* E = enc + (size_t)b * TENC * DIM;

#pragma unroll
    for (int i = 0; i < 4; ++i) {
        const int t = t0 + tr + 16 * i;
        float4 x = *(const float4*)&E[(size_t)t * DIM + d0 + dc];
        float xs[4] = {x.x, x.y, x.z, x.w};
        unsigned int h[4], l[4];
#pragma unroll
        for (int j = 0; j < 4; ++j) split2(xs[j], h[j], l[j]);
        ushort_t* ph = &encH[((size_t)b * TENC + t) * DIM + d0 + dc];
        ushort_t* pl = &encL[((size_t)b * TENC + t) * DIM + d0 + dc];
        *(uint2*)ph = make_uint2(h[0] | (h[1] << 16), h[2] | (h[3] << 16));
        *(uint2*)pl = make_uint2(l[0] | (l[1] << 16), l[2] | (l[3] << 16));
        const int tloc = tr + 16 * i;
#pragma unroll
        for (int j = 0; j < 4; ++j) T[dc + j][tloc] = (ushort_t)h[j];
    }
    __syncthreads();

    const int dr = tid >> 2;
    const int tc = (tid & 3) * 16;
    short8 v0 = *(const short8*)&T[dr][tc];
    short8 v1 = *(const short8*)&T[dr][tc + 8];
    ushort_t* out = &encT[((size_t)b * DIM + d0 + dr) * TENC + t0 + tc];
    *(short8*)out = v0;
    *(short8*)(out + 8) = v1;
}

// ---------------------------------------------------------------------------
__global__ __launch_bounds__(256) void prep_dec(
    const float* __restrict__ dec, ushort_t* __restrict__ decH,
    ushort_t* __restrict__ decL)
{
    const size_t i4 = (size_t)blockIdx.x * 256 + threadIdx.x;
    float4 x = *(const float4*)(dec + i4 * 4);
    float xs[4] = {x.x, x.y, x.z, x.w};
    unsigned int h[4], l[4];
#pragma unroll
    for (int j = 0; j < 4; ++j) split2(xs[j], h[j], l[j]);
    *(uint2*)(decH + i4 * 4) = make_uint2(h[0] | (h[1] << 16), h[2] | (h[3] << 16));
    *(uint2*)(decL + i4 * 4) = make_uint2(l[0] | (l[1] << 16), l[2] | (l[3] << 16));
}

// ---------------------------------------------------------------------------
// gemm1_lds: raw[b,t,u] = enc·dec (split-bf16) - mask.
// Chunk-major LDS: each 16-row group is 1KB; slot(q,r) = q*256B + r*16B.
// Staging lane L = (chunk L>>4, row L&15) -> global (row, k+chunk*8);
// global_load_lds puts lane L at base+16L which IS slot(L>>4, L&15).
// Fragment read (lr,q) -> q*128+lr*8 shorts: wave covers the full 1KB,
// every bank exactly 8x = structural minimum, zero conflicts.
// Fused per-column (max, sum-exp) partial-stat epilogue -> pm/ps.
// ---------------------------------------------------------------------------
__global__ __launch_bounds__(256) void gemm1_lds(
    const ushort_t* __restrict__ encH, const ushort_t* __restrict__ encL,
    const ushort_t* __restrict__ decH, const ushort_t* __restrict__ decL,
    const int* __restrict__ mask, float* __restrict__ raw,
    float* __restrict__ pm, float* __restrict__ ps)
{
    __shared__ __align__(16) ushort_t Ah[128 * 32];
    __shared__ __align__(16) ushort_t Al[128 * 32];
    __shared__ __align__(16) ushort_t Bh[128 * 32];
    __shared__ __align__(16) ushort_t Bl[128 * 32];
    __shared__ float smx[4][68];
    __shared__ float ssx[4][68];

    const int b  = blockIdx.z;
    const int m0 = blockIdx.y * 128;   // t
    const int n0 = blockIdx.x * 128;   // u
    const int tid = threadIdx.x;

    const int lane = tid & 63;
    const int w    = tid >> 6;
    const int wm   = (w & 1) * 64;
    const int wn   = (w >> 1) * 64;
    const int lr   = lane & 15;
    const int q    = lane >> 4;

    // chunk-major staging lane mapping
    const int srow   = lane & 15;       // row within 16-row group
    const int schunk = (lane >> 4) * 8; // k offset (shorts)

    // fragment read base (shorts): group base + q*128 + lr*8
    const int fa = wm * 32 + q * 128 + lr * 8;
    const int fb = wn * 32 + q * 128 + lr * 8;

    const ushort_t* AH = encH + (size_t)b * TENC * DIM;
    const ushort_t* AL = encL + (size_t)b * TENC * DIM;
    const ushort_t* BH = decH + (size_t)b * TDEC * DIM;
    const ushort_t* BL = decL + (size_t)b * TDEC * DIM;
    float* C = raw + (size_t)b * TENC * TDEC;

    f32x4 acc[4][4] = {};

    for (int k0 = 0; k0 < DIM; k0 += 32) {
        __syncthreads();
#pragma unroll
        for (int q2 = 0; q2 < 2; ++q2) {
            const int rg  = w * 2 + q2;            // 16-row group 0..7
            const int row = rg * 16 + srow;
            const size_t ga = (size_t)(m0 + row) * DIM + k0 + schunk;
            const size_t gb = (size_t)(n0 + row) * DIM + k0 + schunk;
            GLOAD16(AH + ga, &Ah[rg * 512]);
            GLOAD16(AL + ga, &Al[rg * 512]);
            GLOAD16(BH + gb, &Bh[rg * 512]);
            GLOAD16(BL + gb, &Bl[rg * 512]);
        }
        __syncthreads();

        short8 ah[4], al[4], bh[4], bl[4];
#pragma unroll
        for (int i = 0; i < 4; ++i) {
            ah[i] = *(const short8*)&Ah[fa + i * 512];
            al[i] = *(const short8*)&Al[fa + i * 512];
            bh[i] = *(const short8*)&Bh[fb + i * 512];
            bl[i] = *(const short8*)&Bl[fb + i * 512];
        }
#pragma unroll
        for (int i = 0; i < 4; ++i)
#pragma unroll
            for (int j = 0; j < 4; ++j) {
                acc[i][j] = __builtin_amdgcn_mfma_f32_16x16x32_bf16(ah[i], bh[j], acc[i][j], 0, 0, 0);
                acc[i][j] = __builtin_amdgcn_mfma_f32_16x16x32_bf16(ah[i], bl[j], acc[i][j], 0, 0, 0);
                acc[i][j] = __builtin_amdgcn_mfma_f32_16x16x32_bf16(al[i], bh[j], acc[i][j], 0, 0, 0);
            }
    }

    // masks per row held by this lane
    float mkv[4][4];
#pragma unroll
    for (int i = 0; i < 4; ++i)
#pragma unroll
        for (int rr = 0; rr < 4; ++rr) {
            const int t = m0 + wm + i * 16 + q * 4 + rr;
            mkv[i][rr] = (mask[b * TENC + t] == 0) ? NEG_BIG : 0.0f;
        }

    // pass 1: store C (C/D layout col=lane&15, row=quad*4+reg) + column max
    float cm[4] = {-INFINITY, -INFINITY, -INFINITY, -INFINITY};
    float cs[4] = {0.f, 0.f, 0.f, 0.f};
#pragma unroll
    for (int i = 0; i < 4; ++i)
#pragma unroll
        for (int rr = 0; rr < 4; ++rr) {
            const int t = m0 + wm + i * 16 + q * 4 + rr;
#pragma unroll
            for (int j = 0; j < 4; ++j) {
                const int u = n0 + wn + j * 16 + lr;
                const float v = acc[i][j][rr] - mkv[i][rr];
                C[(size_t)t * TDEC + u] = v;
                cm[j] = fmaxf(cm[j], v);
            }
        }
    // pass 2: column sum of exp
#pragma unroll
    for (int i = 0; i < 4; ++i)
#pragma unroll
        for (int rr = 0; rr < 4; ++rr)
#pragma unroll
            for (int j = 0; j < 4; ++j)
                cs[j] += __expf(acc[i][j][rr] - mkv[i][rr] - cm[j]);

    // combine across the 4 q-groups (lanes lr, lr+16, lr+32, lr+48)
#pragma unroll
    for (int j = 0; j < 4; ++j) {
#pragma unroll
        for (int d = 16; d < 64; d <<= 1) {
            float om = __shfl_xor(cm[j], d, 64);
            float os = __shfl_xor(cs[j], d, 64);
            float mn = fmaxf(cm[j], om);
            cs[j] = cs[j] * __expf(cm[j] - mn) + os * __expf(om - mn);
            cm[j] = mn;
        }
    }

    // combine the two waves covering the same 64 columns
    if (q == 0) {
#pragma unroll
        for (int j = 0; j < 4; ++j) {
            smx[w][j * 16 + lr] = cm[j];
            ssx[w][j * 16 + lr] = cs[j];
        }
    }
    __syncthreads();
    if (tid < 128) {
        const int col = tid;
        const int wp  = (col >> 6) * 2;
        const int ci  = col & 63;
        const float m1 = smx[wp][ci],     s1 = ssx[wp][ci];
        const float m2 = smx[wp + 1][ci], s2 = ssx[wp + 1][ci];
        const float M = fmaxf(m1, m2);
        const float S = s1 * __expf(m1 - M) + s2 * __expf(m2 - M);
        const int idx = b * TDEC + n0 + col;
        const int tb  = m0 >> 7;
        pm[(size_t)tb * (BATCH * TDEC) + idx] = M;
        ps[(size_t)tb * (BATCH * TDEC) + idx] = S;
    }
}

// ---------------------------------------------------------------------------
// colstat2: combine 16 per-t-block partials -> colM, colI. 4096 columns.
// ---------------------------------------------------------------------------
__global__ __launch_bounds__(256) void colstat2(
    const float* __restrict__ pm, const float* __restrict__ ps,
    float* __restrict__ colM, float* __restrict__ colI)
{
    const int idx = blockIdx.x * 256 + threadIdx.x;
    float M = -INFINITY;
#pragma unroll
    for (int z = 0; z < 16; ++z)
        M = fmaxf(M, pm[(size_t)z * (BATCH * TDEC) + idx]);
    float s = 0.0f;
#pragma unroll
    for (int z = 0; z < 16; ++z)
        s += ps[(size_t)z * (BATCH * TDEC) + idx] *
             __expf(pm[(size_t)z * (BATCH * TDEC) + idx] - M);
    colM[idx] = M;
    colI[idx] = 1.0f / s;
}

// ---------------------------------------------------------------------------
// norm: scores = exp(raw-M)*inv in place (fp32) + scoresT bf16 [u][t].
// ---------------------------------------------------------------------------
__global__ __launch_bounds__(256) void norm_kernel(
    float* __restrict__ S, const float* __restrict__ colM,
    const float* __restrict__ colI, ushort_t* __restrict__ scoresT)
{
    __shared__ ushort_t T[64][72];

    const int b  = blockIdx.z;
    const int t0 = blockIdx.x * 64;
    const int u0 = blockIdx.y * 64;
    const int tid = threadIdx.x;

    const int tr  = tid >> 4;
    const int ucl = (tid & 15) * 4;

    float4 M4 = *(const float4*)&colM[b * TDEC + u0 + ucl];
    float4 I4 = *(const float4*)&colI[b * TDEC + u0 + ucl];

    float* base = S + (size_t)b * TENC * TDEC;

#pragma unroll
    for (int i = 0; i < 4; ++i) {
        const int t = t0 + tr + 16 * i;
        float4 x = *(const float4*)&base[(size_t)t * TDEC + u0 + ucl];
        float4 p;
        p.x = __expf(x.x - M4.x) * I4.x;
        p.y = __expf(x.y - M4.y) * I4.y;
        p.z = __expf(x.z - M4.z) * I4.z;
        p.w = __expf(x.w - M4.w) * I4.w;
        *(float4*)&base[(size_t)t * TDEC + u0 + ucl] = p;
        const int tloc = tr + 16 * i;
        T[ucl + 0][tloc] = (ushort_t)bf16rn(p.x);
        T[ucl + 1][tloc] = (ushort_t)bf16rn(p.y);
        T[ucl + 2][tloc] = (ushort_t)bf16rn(p.z);
        T[ucl + 3][tloc] = (ushort_t)bf16rn(p.w);
    }
    __syncthreads();

    const int ur = tid >> 2;
    const int tc = (tid & 3) * 16;
    short8 v0 = *(const short8*)&T[ur][tc];
    short8 v1 = *(const short8*)&T[ur][tc + 8];
    ushort_t* out = &scoresT[((size_t)b * TDEC + u0 + ur) * TENC + t0 + tc];
    *(short8*)out = v0;
    *(short8*)(out + 8) = v1;
}

// ---------------------------------------------------------------------------
// gemm2_lds: partial[ks][b,u,d] = sum_{t in slice} scoresT[b,u,t]*encT[b,d,t]
// bf16 single, 128x128 tile, BK=32, split-K=2, chunk-major LDS, NO atomics.
// Grid (8, 4, 16): z = b*2 + ks. Each slice: 32 k-iters.
// ---------------------------------------------------------------------------
__global__ __launch_bounds__(256) void gemm2_lds(
    const ushort_t* __restrict__ scoresT, const ushort_t* __restrict__ encT,
    float* __restrict__ p0, float* __restrict__ p1)
{
    __shared__ __align__(16) ushort_t Ah[128 * 32];
    __shared__ __align__(16) ushort_t Bh[128 * 32];

    const int b  = blockIdx.z >> 1;
    const int ks = blockIdx.z & 1;
    const int m0 = blockIdx.y * 128;   // u
    const int n0 = blockIdx.x * 128;   // d
    const int tid = threadIdx.x;

    const int lane = tid & 63;
    const int w    = tid >> 6;
    const int wm   = (w & 1) * 64;
    const int wn   = (w >> 1) * 64;
    const int lr   = lane & 15;
    const int q    = lane >> 4;

    const int srow   = lane & 15;
    const int schunk = (lane >> 4) * 8;
    const int fa = wm * 32 + q * 128 + lr * 8;
    const int fb = wn * 32 + q * 128 + lr * 8;

    const ushort_t* A = scoresT + (size_t)b * TDEC * TENC;
    const ushort_t* B = encT    + (size_t)b * DIM * TENC;
    float* P = (ks ? p1 : p0) + (size_t)b * TDEC * DIM;

    const int kbeg = ks * (TENC / 2);
    const int kend = kbeg + TENC / 2;

    f32x4 acc[4][4] = {};

    for (int k0 = kbeg; k0 < kend; k0 += 32) {
        __syncthreads();
#pragma unroll
        for (int q2 = 0; q2 < 2; ++q2) {
            const int rg  = w * 2 + q2;
            const int row = rg * 16 + srow;
            GLOAD16(A + (size_t)(m0 + row) * TENC + k0 + schunk, &Ah[rg * 512]);
            GLOAD16(B + (size_t)(n0 + row) * TENC + k0 + schunk, &Bh[rg * 512]);
        }
        __syncthreads();

        short8 ah[4], bh[4];
#pragma unroll
        for (int i = 0; i < 4; ++i) {
            ah[i] = *(const short8*)&Ah[fa + i * 512];
            bh[i] = *(const short8*)&Bh[fb + i * 512];
        }
#pragma unroll
        for (int i = 0; i < 4; ++i)
#pragma unroll
            for (int j = 0; j < 4; ++j)
                acc[i][j] = __builtin_amdgcn_mfma_f32_16x16x32_bf16(ah[i], bh[j], acc[i][j], 0, 0, 0);
    }

#pragma unroll
    for (int i = 0; i < 4; ++i)
#pragma unroll
        for (int rr = 0; rr < 4; ++rr) {
            const int u = m0 + wm + i * 16 + q * 4 + rr;
#pragma unroll
            for (int j = 0; j < 4; ++j) {
                const int d = n0 + wn + j * 16 + lr;
                P[(size_t)u * DIM + d] = acc[i][j][rr];
            }
        }
}

// ---------------------------------------------------------------------------
// reduce_ctx: context = p0 + p1 (float4 streaming). 4M floats.
// ---------------------------------------------------------------------------
__global__ __launch_bounds__(256) void reduce_ctx(
    const float* __restrict__ p0, const float* __restrict__ p1,
    float* __restrict__ ctx)
{
    const size_t i4 = ((size_t)blockIdx.x * 256 + threadIdx.x) * 4;
    float4 a = *(const float4*)(p0 + i4);
    float4 b = *(const float4*)(p1 + i4);
    float4 o;
    o.x = a.x + b.x; o.y = a.y + b.y; o.z = a.z + b.z; o.w = a.w + b.w;
    *(float4*)(ctx + i4) = o;
}

// ===========================================================================
// FALLBACK PATH (round-2 proven kernels; used if workspace is too small)
// ===========================================================================

__device__ __forceinline__ void store8(ushort_t* ph, ushort_t* pl,
                                       float4 x0, float4 x1) {
    float xs[8] = {x0.x, x0.y, x0.z, x0.w, x1.x, x1.y, x1.z, x1.w};
    short8 hv, lv;
#pragma unroll
    for (int i = 0; i < 8; ++i) {
        unsigned int h, l;
        split2(xs[i], h, l);
        hv[i] = (short)h;
        lv[i] = (short)l;
    }
    *(short8*)ph = hv;
    *(short8*)pl = lv;
}

__device__ __forceinline__ void wr4(ushort_t* ph, ushort_t* pl, const float* x) {
    unsigned int h[4], l[4];
#pragma unroll
    for (int i = 0; i < 4; ++i) split2(x[i], h[i], l[i]);
    *(uint2*)ph = make_uint2(h[0] | (h[1] << 16), h[2] | (h[3] << 16));
    *(uint2*)pl = make_uint2(l[0] | (l[1] << 16), l[2] | (l[3] << 16));
}

__device__ __forceinline__ short8 frag8B(const ushort_t* p) {
    union { short8 v; uint2 u[2]; } f;
    f.u[0] = *(const uint2*)p;
    f.u[1] = *(const uint2*)(p + 4);
    return f.v;
}

__global__ __launch_bounds__(256) void gemm1_mfma(
    const float* __restrict__ enc, const float* __restrict__ dec,
    const int* __restrict__ mask, float* __restrict__ raw)
{
    __shared__ __align__(16) ushort_t Ah[128 * 32];
    __shared__ __align__(16) ushort_t Al[128 * 32];
    __shared__ __align__(16) ushort_t Bh[128 * 32];
    __shared__ __align__(16) ushort_t Bl[128 * 32];

    const int b  = blockIdx.z;
    const int m0 = blockIdx.y * 128;
    const int n0 = blockIdx.x * 128;
    const int tid = threadIdx.x;

    const float* A  = enc + (size_t)b * TENC * DIM;
    const float* Bg = dec + (size_t)b * TDEC * DIM;
    float*       C  = raw + (size_t)b * TENC * TDEC;

    const int lane = tid & 63;
    const int wv   = tid >> 6;
    const int wm   = (wv & 1) * 64;
    const int wn   = (wv >> 1) * 64;
    const int lr   = lane & 15;
    const int q    = lane >> 4;

    const int r0 = tid >> 2;
    const int c8 = (tid & 3) * 8;

    f32x4 acc[4][4] = {};

    for (int k0 = 0; k0 < DIM; k0 += 32) {
        const float* pa0 = A  + (size_t)(m0 + r0) * DIM + k0 + c8;
        const float* pa1 = A  + (size_t)(m0 + r0 + 64) * DIM + k0 + c8;
        const float* pb0 = Bg + (size_t)(n0 + r0) * DIM + k0 + c8;
        const float* pb1 = Bg + (size_t)(n0 + r0 + 64) * DIM + k0 + c8;
        float4 a0 = *(const float4*)pa0, a0b = *(const float4*)(pa0 + 4);
        float4 a1 = *(const float4*)pa1, a1b = *(const float4*)(pa1 + 4);
        float4 b0 = *(const float4*)pb0, b0b = *(const float4*)(pb0 + 4);
        float4 b1 = *(const float4*)pb1, b1b = *(const float4*)(pb1 + 4);

        __syncthreads();
        store8(&Ah[r0 * 32 + c8],        &Al[r0 * 32 + c8],        a0, a0b);
        store8(&Ah[(r0 + 64) * 32 + c8], &Al[(r0 + 64) * 32 + c8], a1, a1b);
        store8(&Bh[r0 * 32 + c8],        &Bl[r0 * 32 + c8],        b0, b0b);
        store8(&Bh[(r0 + 64) * 32 + c8], &Bl[(r0 + 64) * 32 + c8], b1, b1b);
        __syncthreads();

        short8 ah[4], al[4], bh[4], bl[4];
#pragma unroll
        for (int i = 0; i < 4; ++i) {
            ah[i] = *(const short8*)&Ah[(wm + i * 16 + lr) * 32 + q * 8];
            al[i] = *(const short8*)&Al[(wm + i * 16 + lr) * 32 + q * 8];
            bh[i] = *(const short8*)&Bh[(wn + i * 16 + lr) * 32 + q * 8];
            bl[i] = *(const short8*)&Bl[(wn + i * 16 + lr) * 32 + q * 8];
        }
#pragma unroll
        for (int i = 0; i < 4; ++i)
#pragma unroll
            for (int j = 0; j < 4; ++j) {
                acc[i][j] = __builtin_amdgcn_mfma_f32_16x16x32_bf16(ah[i], bh[j], acc[i][j], 0, 0, 0);
                acc[i][j] = __builtin_amdgcn_mfma_f32_16x16x32_bf16(ah[i], bl[j], acc[i][j], 0, 0, 0);
                acc[i][j] = __builtin_amdgcn_mfma_f32_16x16x32_bf16(al[i], bh[j], acc[i][j], 0, 0, 0);
            }
    }

#pragma unroll
    for (int i = 0; i < 4; ++i)
#pragma unroll
        for (int rr = 0; rr < 4; ++rr) {
            const int t = m0 + wm + i * 16 + q * 4 + rr;
            const float mk = (mask[b * TENC + t] == 0) ? NEG_BIG : 0.0f;
#pragma unroll
            for (int j = 0; j < 4; ++j) {
                const int u = n0 + wn + j * 16 + lr;
                C[(size_t)t * TDEC + u] = acc[i][j][rr] - mk;
            }
        }
}

__global__ __launch_bounds__(256) void softmax_kernel(float* __restrict__ S)
{
    const int b  = blockIdx.y;
    const int u0 = blockIdx.x * 16;
    const int up = threadIdx.x & 15;
    const int tg = threadIdx.x >> 4;

    float* col = S + (size_t)b * TENC * TDEC + u0;

    float m = -INFINITY, s = 0.0f;
    for (int t = tg; t < TENC; t += 16) {
        float x = col[(size_t)t * TDEC + up];
        float mn = fmaxf(m, x);
        s = s * __expf(m - mn) + __expf(x - mn);
        m = mn;
    }

    __shared__ float sm[16][17];
    __shared__ float ss[16][17];
    sm[tg][up] = m;
    ss[tg][up] = s;
    __syncthreads();

    float M = -INFINITY;
#pragma unroll
    for (int j = 0; j < 16; ++j) M = fmaxf(M, sm[j][up]);
    float sum = 0.0f;
#pragma unroll
    for (int j = 0; j < 16; ++j) sum += ss[j][up] * __expf(sm[j][up] - M);
    const float inv = 1.0f / sum;

    for (int t = tg; t < TENC; t += 16) {
        float x = col[(size_t)t * TDEC + up];
        col[(size_t)t * TDEC + up] = __expf(x - M) * inv;
    }
}

#define G2_LD 36

__global__ __launch_bounds__(256) void gemm2_mfma(
    const float* __restrict__ scores, const float* __restrict__ enc,
    float* __restrict__ context)
{
    __shared__ __align__(16) ushort_t Ah[128 * G2_LD];
    __shared__ __align__(16) ushort_t Al[128 * G2_LD];
    __shared__ __align__(16) ushort_t Bh[128 * G2_LD];
    __shared__ __align__(16) ushort_t Bl[128 * G2_LD];

    const int b  = blockIdx.z;
    const int m0 = blockIdx.y * 128;
    const int n0 = blockIdx.x * 128;
    const int tid = threadIdx.x;

    const float* S = scores + (size_t)b * TENC * TDEC;
    const float* E = enc    + (size_t)b * TENC * DIM;
    float*       C = context + (size_t)b * TDEC * DIM;

    const int lane = tid & 63;
    const int wv   = tid >> 6;
    const int wm   = (wv & 1) * 64;
    const int wn   = (wv >> 1) * 64;
    const int lr   = lane & 15;
    const int q    = lane >> 4;

    const int ul = tid & 127;
    const int th = (tid >> 7) * 16;

    f32x4 acc[4][4] = {};

    for (int k0 = 0; k0 < TENC; k0 += 32) {
        float av[16], bv[16];
#pragma unroll
        for (int i = 0; i < 4; ++i) {
            const int t = k0 + th + i * 4;
#pragma unroll
            for (int j = 0; j < 4; ++j) {
                av[i * 4 + j] = S[(size_t)(t + j) * TDEC + m0 + ul];
                bv[i * 4 + j] = E[(size_t)(t + j) * DIM + n0 + ul];
            }
        }
        __syncthreads();
#pragma unroll
        for (int i = 0; i < 4; ++i) {
            const int tt = th + i * 4;
            wr4(&Ah[ul * G2_LD + tt], &Al[ul * G2_LD + tt], &av[i * 4]);
            wr4(&Bh[ul * G2_LD + tt], &Bl[ul * G2_LD + tt], &bv[i * 4]);
        }
        __syncthreads();

        short8 ah[4], al[4], bh[4], bl[4];
#pragma unroll
        for (int i = 0; i < 4; ++i) {
            ah[i] = frag8B(&Ah[(wm + i * 16 + lr) * G2_LD + q * 8]);
            al[i] = frag8B(&Al[(wm + i * 16 + lr) * G2_LD + q * 8]);
            bh[i] = frag8B(&Bh[(wn + i * 16 + lr) * G2_LD + q * 8]);
            bl[i] = frag8B(&Bl[(wn + i * 16 + lr) * G2_LD + q * 8]);
        }
#pragma unroll
        for (int i = 0; i < 4; ++i)
#pragma unroll
            for (int j = 0; j < 4; ++j) {
                acc[i][j] = __builtin_amdgcn_mfma_f32_16x16x32_bf16(ah[i], bh[j], acc[i][j], 0, 0, 0);
                acc[i][j] = __builtin_amdgcn_mfma_f32_16x16x32_bf16(ah[i], bl[j], acc[i][j], 0, 0, 0);
                acc[i][j] = __builtin_amdgcn_mfma_f32_16x16x32_bf16(al[i], bh[j], acc[i][j], 0, 0, 0);
            }
    }

#pragma unroll
    for (int i = 0; i < 4; ++i)
#pragma unroll
        for (int rr = 0; rr < 4; ++rr) {
            const int u = m0 + wm + i * 16 + q * 4 + rr;
#pragma unroll
            for (int j = 0; j < 4; ++j) {
                const int d = n0 + wn + j * 16 + lr;
                C[(size_t)u * DIM + d] = acc[i][j][rr];
            }
        }
}

// ===========================================================================
extern "C" void kernel_launch(void* const* d_in, const int* in_sizes, int n_in,
                              void* d_out, int out_size, void* d_ws, size_t ws_size,
                              hipStream_t stream)
{
    const float* enc      = (const float*)d_in[0];
    const int*   enc_mask = (const int*)  d_in[1];
    const float* dec      = (const float*)d_in[2];

    float* context = (float*)d_out;                        // B*TDEC*DIM
    float* scores  = context + (size_t)BATCH * TDEC * DIM; // B*TENC*TDEC

    // workspace layout (bytes).
    // pm/ps overlay scoresT (consumed by colstat2 before norm writes scoresT).
    // p0/p1 overlay encH/encL (dead after gemm1; each partial is 16 MiB).
    const size_t OFF_ENC_H = 0;
    const size_t OFF_ENC_L = 33554432;
    const size_t OFF_DEC_H = 67108864;
    const size_t OFF_DEC_L = 75497472;
    const size_t OFF_ENC_T = 83886080;
    const size_t OFF_SCO_T = 117440512;
    const size_t OFF_PM    = OFF_SCO_T;            // 16*4096 floats = 256 KB
    const size_t OFF_PS    = OFF_SCO_T + 262144;   // 256 KB
    const size_t OFF_COL_M = 134217728;
    const size_t OFF_COL_I = 134234112;
    const size_t WS_NEED   = 134381568;

    if (ws_size >= WS_NEED) {
        char* w = (char*)d_ws;
        ushort_t* encH    = (ushort_t*)(w + OFF_ENC_H);
        ushort_t* encL    = (ushort_t*)(w + OFF_ENC_L);
        ushort_t* decH    = (ushort_t*)(w + OFF_DEC_H);
        ushort_t* decL    = (ushort_t*)(w + OFF_DEC_L);
        ushort_t* encT    = (ushort_t*)(w + OFF_ENC_T);
        ushort_t* scoresT = (ushort_t*)(w + OFF_SCO_T);
        float*    pm      = (float*)(w + OFF_PM);
        float*    ps      = (float*)(w + OFF_PS);
        float*    colM    = (float*)(w + OFF_COL_M);
        float*    colI    = (float*)(w + OFF_COL_I);
        float*    part0   = (float*)(w + OFF_ENC_H);   // overlay, 16 MiB
        float*    part1   = (float*)(w + OFF_ENC_L);   // overlay, 16 MiB

        prep_enc<<<dim3(DIM / 64, TENC / 64, BATCH), 256, 0, stream>>>(
            enc, encH, encL, encT);
        prep_dec<<<4096, 256, 0, stream>>>(dec, decH, decL);

        gemm1_lds<<<dim3(TDEC / 128, TENC / 128, BATCH), 256, 0, stream>>>(
            encH, encL, decH, decL, enc_mask, scores, pm, ps);

        colstat2<<<16, 256, 0, stream>>>(pm, ps, colM, colI);

        norm_kernel<<<dim3(TENC / 64, TDEC / 64, BATCH), 256, 0, stream>>>(
            scores, colM, colI, scoresT);

        gemm2_lds<<<dim3(DIM / 128, TDEC / 128, BATCH * 2), 256, 0, stream>>>(
            scoresT, encT, part0, part1);

        reduce_ctx<<<4096, 256, 0, stream>>>(part0, part1, context);
    } else {
        gemm1_mfma<<<dim3(TDEC / 128, TENC / 128, BATCH), 256, 0, stream>>>(
            enc, dec, enc_mask, scores);
        softmax_kernel<<<dim3(TDEC / 16, BATCH), 256, 0, stream>>>(scores);
        gemm2_mfma<<<dim3(DIM / 128, TDEC / 128, BATCH), 256, 0, stream>>>(
            scores, enc, context);
    }
}

// Round 6
// 240.014 us; speedup vs baseline: 1.2076x; 1.1311x over previous
//
#include <hip/hip_runtime.h>
#include <math.h>

#define BATCH 8
#define TENC 2048
#define TDEC 512
#define DIM 1024
#define NEG_BIG 1e20f

typedef __attribute__((ext_vector_type(8))) short short8;
typedef __attribute__((ext_vector_type(4))) float f32x4;
typedef unsigned short ushort_t;

// ---- fp32 -> bf16 helpers --------------------------------------------------
__device__ __forceinline__ unsigned int bf16rn(float x) {
    unsigned int u = __float_as_uint(x);
    return (u + 0x7FFFu + ((u >> 16) & 1u)) >> 16;
}
__device__ __forceinline__ float bf16f(unsigned int b) {
    return __uint_as_float(b << 16);
}
__device__ __forceinline__ void split2(float x, unsigned int& h, unsigned int& l) {
    h = bf16rn(x);
    l = bf16rn(x - bf16f(h));
}

// async global(bf16) -> LDS, 16B/lane, wave-uniform LDS base
#define GLOAD16(g, l)                                                        \
    __builtin_amdgcn_global_load_lds(                                        \
        (const __attribute__((address_space(1))) unsigned int*)(g),          \
        (__attribute__((address_space(3))) unsigned int*)(l), 16, 0, 0)

// Tiled ("fragment-linear") operand layout:
//   matrix [ROWS][K] -> tiles of 16 rows x 32 k, tile = 512 shorts (1 KB).
//   tile index = (row>>4)*(K/32) + (k>>5)
//   within tile: elem(r, 8q+j) at shorts q*128 + r*8 + j   (q=(k>>3)&3)
// A staging wave reads tile_base + lane*8 shorts (one contiguous 1 KB) and
// global_load_lds lands lane L at LDS base+16L -> fragment read for MFMA lane
// (lr,q) is q*128+lr*8 = 16*lane: linear, conflict-free (measured r5), and
// global is perfectly coalesced (fixes r5's 2KB-stride scatter).
__device__ __forceinline__ size_t tiled_off(int row, int k, int ntK) {
    return ((size_t)(row >> 4) * ntK + (k >> 5)) * 512
         + ((k >> 3) & 3) * 128 + (row & 15) * 8;
}

// ===========================================================================
// PRIMARY PATH (needs ~128.2 MiB workspace)
// ===========================================================================

// ---------------------------------------------------------------------------
// prep_enc: enc fp32 [b][t][d] -> encH/encL tiled (rows=t, K=d, ntK=32)
//                               + encT  tiled (rows=d, K=t, ntK=64), hi only.
// Grid (DIM/64, TENC/64, BATCH), 256 threads.
// ---------------------------------------------------------------------------
__global__ __launch_bounds__(256) void prep_enc(
    const float* __restrict__ enc, ushort_t* __restrict__ encH,
    ushort_t* __restrict__ encL, ushort_t* __restrict__ encT)
{
    __shared__ ushort_t T[64][72];   // [d][t]

    const int b  = blockIdx.z;
    const int t0 = blockIdx.y * 64;
    const int d0 = blockIdx.x * 64;
    const int tid = threadIdx.x;

    const float* E = enc + (size_t)b * TENC * DIM;
    const size_t bofs1 = (size_t)b * TENC * DIM;   // encH/encL batch offset
    const size_t bofs2 = (size_t)b * DIM * TENC;   // encT batch offset

    const int ltr = tid >> 2;          // 0..63 t-row

#pragma unroll
    for (int it = 0; it < 2; ++it) {
        const int c  = (tid & 3) + it * 4;   // 0..7: chunk of 8 d
        const int gt = t0 + ltr;
        const int gd = d0 + c * 8;
        float4 x0 = *(const float4*)&E[(size_t)gt * DIM + gd];
        float4 x1 = *(const float4*)&E[(size_t)gt * DIM + gd + 4];
        float xs[8] = {x0.x, x0.y, x0.z, x0.w, x1.x, x1.y, x1.z, x1.w};
        unsigned int h[8], l[8];
        short8 hv, lv;
#pragma unroll
        for (int j = 0; j < 8; ++j) {
            split2(xs[j], h[j], l[j]);
            hv[j] = (short)h[j];
            lv[j] = (short)l[j];
        }
        const size_t off = bofs1 + tiled_off(gt, gd, DIM / 32);
        *(short8*)&encH[off] = hv;
        *(short8*)&encL[off] = lv;
#pragma unroll
        for (int j = 0; j < 8; ++j) T[c * 8 + j][ltr] = (ushort_t)h[j];
    }
    __syncthreads();

    const int dr = tid >> 2;           // 0..63 d-row
#pragma unroll
    for (int it = 0; it < 2; ++it) {
        const int tc = (tid & 3) + it * 4;   // 0..7: chunk of 8 t
        const int gd = d0 + dr;
        const int gt = t0 + tc * 8;
        short8 v = *(const short8*)&T[dr][tc * 8];
        *(short8*)&encT[bofs2 + tiled_off(gd, gt, TENC / 32)] = v;
    }
}

// ---------------------------------------------------------------------------
// prep_dec: dec fp32 [b][u][d] -> decH/decL tiled (rows=u, K=d, ntK=32).
// Grid (DIM/64, TDEC/64, BATCH), 256 threads.
// ---------------------------------------------------------------------------
__global__ __launch_bounds__(256) void prep_dec(
    const float* __restrict__ dec, ushort_t* __restrict__ decH,
    ushort_t* __restrict__ decL)
{
    const int b  = blockIdx.z;
    const int u0 = blockIdx.y * 64;
    const int d0 = blockIdx.x * 64;
    const int tid = threadIdx.x;

    const float* D = dec + (size_t)b * TDEC * DIM;
    const size_t bofs = (size_t)b * TDEC * DIM;

    const int lur = tid >> 2;          // 0..63 u-row

#pragma unroll
    for (int it = 0; it < 2; ++it) {
        const int c  = (tid & 3) + it * 4;
        const int gu = u0 + lur;
        const int gd = d0 + c * 8;
        float4 x0 = *(const float4*)&D[(size_t)gu * DIM + gd];
        float4 x1 = *(const float4*)&D[(size_t)gu * DIM + gd + 4];
        float xs[8] = {x0.x, x0.y, x0.z, x0.w, x1.x, x1.y, x1.z, x1.w};
        short8 hv, lv;
#pragma unroll
        for (int j = 0; j < 8; ++j) {
            unsigned int h, l;
            split2(xs[j], h, l);
            hv[j] = (short)h;
            lv[j] = (short)l;
        }
        const size_t off = bofs + tiled_off(gu, gd, DIM / 32);
        *(short8*)&decH[off] = hv;
        *(short8*)&decL[off] = lv;
    }
}

// ---------------------------------------------------------------------------
// gemm1_lds: raw[b,t,u] = enc·dec (split-bf16) - mask. Tiled operands:
// staging = 1 contiguous 1KB tile per wave-GLOAD16, LDS linear, zero-conflict
// fragment reads. Fused per-column (max,sum-exp) partial stats -> pm/ps.
// ---------------------------------------------------------------------------
__global__ __launch_bounds__(256) void gemm1_lds(
    const ushort_t* __restrict__ encH, const ushort_t* __restrict__ encL,
    const ushort_t* __restrict__ decH, const ushort_t* __restrict__ decL,
    const int* __restrict__ mask, float* __restrict__ raw,
    float* __restrict__ pm, float* __restrict__ ps)
{
    __shared__ __align__(16) ushort_t Ah[128 * 32];
    __shared__ __align__(16) ushort_t Al[128 * 32];
    __shared__ __align__(16) ushort_t Bh[128 * 32];
    __shared__ __align__(16) ushort_t Bl[128 * 32];
    __shared__ float smx[4][68];
    __shared__ float ssx[4][68];

    const int b  = blockIdx.z;
    const int m0 = blockIdx.y * 128;   // t
    const int n0 = blockIdx.x * 128;   // u
    const int tid = threadIdx.x;

    const int lane = tid & 63;
    const int w    = tid >> 6;
    const int wm   = (w & 1) * 64;
    const int wn   = (w >> 1) * 64;
    const int lr   = lane & 15;
    const int q    = lane >> 4;
    const int l8   = lane * 8;         // shorts within a 1KB tile

    const int fa = wm * 32 + q * 128 + lr * 8;
    const int fb = wn * 32 + q * 128 + lr * 8;

    const ushort_t* AH = encH + (size_t)b * TENC * DIM;
    const ushort_t* AL = encL + (size_t)b * TENC * DIM;
    const ushort_t* BH = decH + (size_t)b * TDEC * DIM;
    const ushort_t* BL = decL + (size_t)b * TDEC * DIM;
    float* C = raw + (size_t)b * TENC * TDEC;

    f32x4 acc[4][4] = {};

    for (int k0 = 0; k0 < DIM; k0 += 32) {
        __syncthreads();
#pragma unroll
        for (int q2 = 0; q2 < 2; ++q2) {
            const int rg = w * 2 + q2;            // 16-row group 0..7
            const size_t tA = ((size_t)((m0 >> 4) + rg) * (DIM / 32) + (k0 >> 5)) * 512 + l8;
            const size_t tB = ((size_t)((n0 >> 4) + rg) * (DIM / 32) + (k0 >> 5)) * 512 + l8;
            GLOAD16(AH + tA, &Ah[rg * 512]);
            GLOAD16(AL + tA, &Al[rg * 512]);
            GLOAD16(BH + tB, &Bh[rg * 512]);
            GLOAD16(BL + tB, &Bl[rg * 512]);
        }
        __syncthreads();

        short8 ah[4], al[4], bh[4], bl[4];
#pragma unroll
        for (int i = 0; i < 4; ++i) {
            ah[i] = *(const short8*)&Ah[fa + i * 512];
            al[i] = *(const short8*)&Al[fa + i * 512];
            bh[i] = *(const short8*)&Bh[fb + i * 512];
            bl[i] = *(const short8*)&Bl[fb + i * 512];
        }
#pragma unroll
        for (int i = 0; i < 4; ++i)
#pragma unroll
            for (int j = 0; j < 4; ++j) {
                acc[i][j] = __builtin_amdgcn_mfma_f32_16x16x32_bf16(ah[i], bh[j], acc[i][j], 0, 0, 0);
                acc[i][j] = __builtin_amdgcn_mfma_f32_16x16x32_bf16(ah[i], bl[j], acc[i][j], 0, 0, 0);
                acc[i][j] = __builtin_amdgcn_mfma_f32_16x16x32_bf16(al[i], bh[j], acc[i][j], 0, 0, 0);
            }
    }

    float mkv[4][4];
#pragma unroll
    for (int i = 0; i < 4; ++i)
#pragma unroll
        for (int rr = 0; rr < 4; ++rr) {
            const int t = m0 + wm + i * 16 + q * 4 + rr;
            mkv[i][rr] = (mask[b * TENC + t] == 0) ? NEG_BIG : 0.0f;
        }

    float cm[4] = {-INFINITY, -INFINITY, -INFINITY, -INFINITY};
    float cs[4] = {0.f, 0.f, 0.f, 0.f};
#pragma unroll
    for (int i = 0; i < 4; ++i)
#pragma unroll
        for (int rr = 0; rr < 4; ++rr) {
            const int t = m0 + wm + i * 16 + q * 4 + rr;
#pragma unroll
            for (int j = 0; j < 4; ++j) {
                const int u = n0 + wn + j * 16 + lr;
                const float v = acc[i][j][rr] - mkv[i][rr];
                C[(size_t)t * TDEC + u] = v;
                cm[j] = fmaxf(cm[j], v);
            }
        }
#pragma unroll
    for (int i = 0; i < 4; ++i)
#pragma unroll
        for (int rr = 0; rr < 4; ++rr)
#pragma unroll
            for (int j = 0; j < 4; ++j)
                cs[j] += __expf(acc[i][j][rr] - mkv[i][rr] - cm[j]);

#pragma unroll
    for (int j = 0; j < 4; ++j) {
#pragma unroll
        for (int d = 16; d < 64; d <<= 1) {
            float om = __shfl_xor(cm[j], d, 64);
            float os = __shfl_xor(cs[j], d, 64);
            float mn = fmaxf(cm[j], om);
            cs[j] = cs[j] * __expf(cm[j] - mn) + os * __expf(om - mn);
            cm[j] = mn;
        }
    }

    if (q == 0) {
#pragma unroll
        for (int j = 0; j < 4; ++j) {
            smx[w][j * 16 + lr] = cm[j];
            ssx[w][j * 16 + lr] = cs[j];
        }
    }
    __syncthreads();
    if (tid < 128) {
        const int col = tid;
        const int wp  = (col >> 6) * 2;
        const int ci  = col & 63;
        const float m1 = smx[wp][ci],     s1 = ssx[wp][ci];
        const float m2 = smx[wp + 1][ci], s2 = ssx[wp + 1][ci];
        const float M = fmaxf(m1, m2);
        const float S = s1 * __expf(m1 - M) + s2 * __expf(m2 - M);
        const int idx = b * TDEC + n0 + col;
        const int tb  = m0 >> 7;
        pm[(size_t)tb * (BATCH * TDEC) + idx] = M;
        ps[(size_t)tb * (BATCH * TDEC) + idx] = S;
    }
}

// ---------------------------------------------------------------------------
__global__ __launch_bounds__(256) void colstat2(
    const float* __restrict__ pm, const float* __restrict__ ps,
    float* __restrict__ colM, float* __restrict__ colI)
{
    const int idx = blockIdx.x * 256 + threadIdx.x;
    float M = -INFINITY;
#pragma unroll
    for (int z = 0; z < 16; ++z)
        M = fmaxf(M, pm[(size_t)z * (BATCH * TDEC) + idx]);
    float s = 0.0f;
#pragma unroll
    for (int z = 0; z < 16; ++z)
        s += ps[(size_t)z * (BATCH * TDEC) + idx] *
             __expf(pm[(size_t)z * (BATCH * TDEC) + idx] - M);
    colM[idx] = M;
    colI[idx] = 1.0f / s;
}

// ---------------------------------------------------------------------------
// norm: scores = exp(raw-M)*inv in place (fp32) + scoresT tiled bf16
// (rows=u, K=t, ntK=64). Grid (TENC/64, TDEC/64, BATCH).
// ---------------------------------------------------------------------------
__global__ __launch_bounds__(256) void norm_kernel(
    float* __restrict__ S, const float* __restrict__ colM,
    const float* __restrict__ colI, ushort_t* __restrict__ scoresT)
{
    __shared__ ushort_t T[64][72];   // [u][t]

    const int b  = blockIdx.z;
    const int t0 = blockIdx.x * 64;
    const int u0 = blockIdx.y * 64;
    const int tid = threadIdx.x;

    const int tr  = tid >> 4;
    const int ucl = (tid & 15) * 4;

    float4 M4 = *(const float4*)&colM[b * TDEC + u0 + ucl];
    float4 I4 = *(const float4*)&colI[b * TDEC + u0 + ucl];

    float* base = S + (size_t)b * TENC * TDEC;

#pragma unroll
    for (int i = 0; i < 4; ++i) {
        const int t = t0 + tr + 16 * i;
        float4 x = *(const float4*)&base[(size_t)t * TDEC + u0 + ucl];
        float4 p;
        p.x = __expf(x.x - M4.x) * I4.x;
        p.y = __expf(x.y - M4.y) * I4.y;
        p.z = __expf(x.z - M4.z) * I4.z;
        p.w = __expf(x.w - M4.w) * I4.w;
        *(float4*)&base[(size_t)t * TDEC + u0 + ucl] = p;
        const int tloc = tr + 16 * i;
        T[ucl + 0][tloc] = (ushort_t)bf16rn(p.x);
        T[ucl + 1][tloc] = (ushort_t)bf16rn(p.y);
        T[ucl + 2][tloc] = (ushort_t)bf16rn(p.z);
        T[ucl + 3][tloc] = (ushort_t)bf16rn(p.w);
    }
    __syncthreads();

    const size_t bofs = (size_t)b * TDEC * TENC;
    const int ur = tid >> 2;
#pragma unroll
    for (int it = 0; it < 2; ++it) {
        const int tc = (tid & 3) + it * 4;   // chunk of 8 t
        const int gu = u0 + ur;
        const int gt = t0 + tc * 8;
        short8 v = *(const short8*)&T[ur][tc * 8];
        *(short8*)&scoresT[bofs + tiled_off(gu, gt, TENC / 32)] = v;
    }
}

// ---------------------------------------------------------------------------
// gemm2_lds: partial[ks] = scoresT·encT^T slice (bf16 single), tiled operands,
// split-K=2, no atomics. Grid (8, 4, 16): z = b*2+ks.
// ---------------------------------------------------------------------------
__global__ __launch_bounds__(256) void gemm2_lds(
    const ushort_t* __restrict__ scoresT, const ushort_t* __restrict__ encT,
    float* __restrict__ p0, float* __restrict__ p1)
{
    __shared__ __align__(16) ushort_t Ah[128 * 32];
    __shared__ __align__(16) ushort_t Bh[128 * 32];

    const int b  = blockIdx.z >> 1;
    const int ks = blockIdx.z & 1;
    const int m0 = blockIdx.y * 128;   // u
    const int n0 = blockIdx.x * 128;   // d
    const int tid = threadIdx.x;

    const int lane = tid & 63;
    const int w    = tid >> 6;
    const int wm   = (w & 1) * 64;
    const int wn   = (w >> 1) * 64;
    const int lr   = lane & 15;
    const int q    = lane >> 4;
    const int l8   = lane * 8;

    const int fa = wm * 32 + q * 128 + lr * 8;
    const int fb = wn * 32 + q * 128 + lr * 8;

    const ushort_t* A = scoresT + (size_t)b * TDEC * TENC;
    const ushort_t* B = encT    + (size_t)b * DIM * TENC;
    float* P = (ks ? p1 : p0) + (size_t)b * TDEC * DIM;

    const int kbeg = ks * (TENC / 2);
    const int kend = kbeg + TENC / 2;

    f32x4 acc[4][4] = {};

    for (int k0 = kbeg; k0 < kend; k0 += 32) {
        __syncthreads();
#pragma unroll
        for (int q2 = 0; q2 < 2; ++q2) {
            const int rg = w * 2 + q2;
            const size_t tA = ((size_t)((m0 >> 4) + rg) * (TENC / 32) + (k0 >> 5)) * 512 + l8;
            const size_t tB = ((size_t)((n0 >> 4) + rg) * (TENC / 32) + (k0 >> 5)) * 512 + l8;
            GLOAD16(A + tA, &Ah[rg * 512]);
            GLOAD16(B + tB, &Bh[rg * 512]);
        }
        __syncthreads();

        short8 ah[4], bh[4];
#pragma unroll
        for (int i = 0; i < 4; ++i) {
            ah[i] = *(const short8*)&Ah[fa + i * 512];
            bh[i] = *(const short8*)&Bh[fb + i * 512];
        }
#pragma unroll
        for (int i = 0; i < 4; ++i)
#pragma unroll
            for (int j = 0; j < 4; ++j)
                acc[i][j] = __builtin_amdgcn_mfma_f32_16x16x32_bf16(ah[i], bh[j], acc[i][j], 0, 0, 0);
    }

#pragma unroll
    for (int i = 0; i < 4; ++i)
#pragma unroll
        for (int rr = 0; rr < 4; ++rr) {
            const int u = m0 + wm + i * 16 + q * 4 + rr;
#pragma unroll
            for (int j = 0; j < 4; ++j) {
                const int d = n0 + wn + j * 16 + lr;
                P[(size_t)u * DIM + d] = acc[i][j][rr];
            }
        }
}

// ---------------------------------------------------------------------------
__global__ __launch_bounds__(256) void reduce_ctx(
    const float* __restrict__ p0, const float* __restrict__ p1,
    float* __restrict__ ctx)
{
    const size_t i4 = ((size_t)blockIdx.x * 256 + threadIdx.x) * 4;
    float4 a = *(const float4*)(p0 + i4);
    float4 b = *(const float4*)(p1 + i4);
    float4 o;
    o.x = a.x + b.x; o.y = a.y + b.y; o.z = a.z + b.z; o.w = a.w + b.w;
    *(float4*)(ctx + i4) = o;
}

// ===========================================================================
// FALLBACK PATH (round-2 proven kernels; used if workspace is too small)
// ===========================================================================

__device__ __forceinline__ void store8(ushort_t* ph, ushort_t* pl,
                                       float4 x0, float4 x1) {
    float xs[8] = {x0.x, x0.y, x0.z, x0.w, x1.x, x1.y, x1.z, x1.w};
    short8 hv, lv;
#pragma unroll
    for (int i = 0; i < 8; ++i) {
        unsigned int h, l;
        split2(xs[i], h, l);
        hv[i] = (short)h;
        lv[i] = (short)l;
    }
    *(short8*)ph = hv;
    *(short8*)pl = lv;
}

__device__ __forceinline__ void wr4(ushort_t* ph, ushort_t* pl, const float* x) {
    unsigned int h[4], l[4];
#pragma unroll
    for (int i = 0; i < 4; ++i) split2(x[i], h[i], l[i]);
    *(uint2*)ph = make_uint2(h[0] | (h[1] << 16), h[2] | (h[3] << 16));
    *(uint2*)pl = make_uint2(l[0] | (l[1] << 16), l[2] | (l[3] << 16));
}

__device__ __forceinline__ short8 frag8B(const ushort_t* p) {
    union { short8 v; uint2 u[2]; } f;
    f.u[0] = *(const uint2*)p;
    f.u[1] = *(const uint2*)(p + 4);
    return f.v;
}

__global__ __launch_bounds__(256) void gemm1_mfma(
    const float* __restrict__ enc, const float* __restrict__ dec,
    const int* __restrict__ mask, float* __restrict__ raw)
{
    __shared__ __align__(16) ushort_t Ah[128 * 32];
    __shared__ __align__(16) ushort_t Al[128 * 32];
    __shared__ __align__(16) ushort_t Bh[128 * 32];
    __shared__ __align__(16) ushort_t Bl[128 * 32];

    const int b  = blockIdx.z;
    const int m0 = blockIdx.y * 128;
    const int n0 = blockIdx.x * 128;
    const int tid = threadIdx.x;

    const float* A  = enc + (size_t)b * TENC * DIM;
    const float* Bg = dec + (size_t)b * TDEC * DIM;
    float*       C  = raw + (size_t)b * TENC * TDEC;

    const int lane = tid & 63;
    const int wv   = tid >> 6;
    const int wm   = (wv & 1) * 64;
    const int wn   = (wv >> 1) * 64;
    const int lr   = lane & 15;
    const int q    = lane >> 4;

    const int r0 = tid >> 2;
    const int c8 = (tid & 3) * 8;

    f32x4 acc[4][4] = {};

    for (int k0 = 0; k0 < DIM; k0 += 32) {
        const float* pa0 = A  + (size_t)(m0 + r0) * DIM + k0 + c8;
        const float* pa1 = A  + (size_t)(m0 + r0 + 64) * DIM + k0 + c8;
        const float* pb0 = Bg + (size_t)(n0 + r0) * DIM + k0 + c8;
        const float* pb1 = Bg + (size_t)(n0 + r0 + 64) * DIM + k0 + c8;
        float4 a0 = *(const float4*)pa0, a0b = *(const float4*)(pa0 + 4);
        float4 a1 = *(const float4*)pa1, a1b = *(const float4*)(pa1 + 4);
        float4 b0 = *(const float4*)pb0, b0b = *(const float4*)(pb0 + 4);
        float4 b1 = *(const float4*)pb1, b1b = *(const float4*)(pb1 + 4);

        __syncthreads();
        store8(&Ah[r0 * 32 + c8],        &Al[r0 * 32 + c8],        a0, a0b);
        store8(&Ah[(r0 + 64) * 32 + c8], &Al[(r0 + 64) * 32 + c8], a1, a1b);
        store8(&Bh[r0 * 32 + c8],        &Bl[r0 * 32 + c8],        b0, b0b);
        store8(&Bh[(r0 + 64) * 32 + c8], &Bl[(r0 + 64) * 32 + c8], b1, b1b);
        __syncthreads();

        short8 ah[4], al[4], bh[4], bl[4];
#pragma unroll
        for (int i = 0; i < 4; ++i) {
            ah[i] = *(const short8*)&Ah[(wm + i * 16 + lr) * 32 + q * 8];
            al[i] = *(const short8*)&Al[(wm + i * 16 + lr) * 32 + q * 8];
            bh[i] = *(const short8*)&Bh[(wn + i * 16 + lr) * 32 + q * 8];
            bl[i] = *(const short8*)&Bl[(wn + i * 16 + lr) * 32 + q * 8];
        }
#pragma unroll
        for (int i = 0; i < 4; ++i)
#pragma unroll
            for (int j = 0; j < 4; ++j) {
                acc[i][j] = __builtin_amdgcn_mfma_f32_16x16x32_bf16(ah[i], bh[j], acc[i][j], 0, 0, 0);
                acc[i][j] = __builtin_amdgcn_mfma_f32_16x16x32_bf16(ah[i], bl[j], acc[i][j], 0, 0, 0);
                acc[i][j] = __builtin_amdgcn_mfma_f32_16x16x32_bf16(al[i], bh[j], acc[i][j], 0, 0, 0);
            }
    }

#pragma unroll
    for (int i = 0; i < 4; ++i)
#pragma unroll
        for (int rr = 0; rr < 4; ++rr) {
            const int t = m0 + wm + i * 16 + q * 4 + rr;
            const float mk = (mask[b * TENC + t] == 0) ? NEG_BIG : 0.0f;
#pragma unroll
            for (int j = 0; j < 4; ++j) {
                const int u = n0 + wn + j * 16 + lr;
                C[(size_t)t * TDEC + u] = acc[i][j][rr] - mk;
            }
        }
}

__global__ __launch_bounds__(256) void softmax_kernel(float* __restrict__ S)
{
    const int b  = blockIdx.y;
    const int u0 = blockIdx.x * 16;
    const int up = threadIdx.x & 15;
    const int tg = threadIdx.x >> 4;

    float* col = S + (size_t)b * TENC * TDEC + u0;

    float m = -INFINITY, s = 0.0f;
    for (int t = tg; t < TENC; t += 16) {
        float x = col[(size_t)t * TDEC + up];
        float mn = fmaxf(m, x);
        s = s * __expf(m - mn) + __expf(x - mn);
        m = mn;
    }

    __shared__ float sm[16][17];
    __shared__ float ss[16][17];
    sm[tg][up] = m;
    ss[tg][up] = s;
    __syncthreads();

    float M = -INFINITY;
#pragma unroll
    for (int j = 0; j < 16; ++j) M = fmaxf(M, sm[j][up]);
    float sum = 0.0f;
#pragma unroll
    for (int j = 0; j < 16; ++j) sum += ss[j][up] * __expf(sm[j][up] - M);
    const float inv = 1.0f / sum;

    for (int t = tg; t < TENC; t += 16) {
        float x = col[(size_t)t * TDEC + up];
        col[(size_t)t * TDEC + up] = __expf(x - M) * inv;
    }
}

#define G2_LD 36

__global__ __launch_bounds__(256) void gemm2_mfma(
    const float* __restrict__ scores, const float* __restrict__ enc,
    float* __restrict__ context)
{
    __shared__ __align__(16) ushort_t Ah[128 * G2_LD];
    __shared__ __align__(16) ushort_t Al[128 * G2_LD];
    __shared__ __align__(16) ushort_t Bh[128 * G2_LD];
    __shared__ __align__(16) ushort_t Bl[128 * G2_LD];

    const int b  = blockIdx.z;
    const int m0 = blockIdx.y * 128;
    const int n0 = blockIdx.x * 128;
    const int tid = threadIdx.x;

    const float* S = scores + (size_t)b * TENC * TDEC;
    const float* E = enc    + (size_t)b * TENC * DIM;
    float*       C = context + (size_t)b * TDEC * DIM;

    const int lane = tid & 63;
    const int wv   = tid >> 6;
    const int wm   = (wv & 1) * 64;
    const int wn   = (wv >> 1) * 64;
    const int lr   = lane & 15;
    const int q    = lane >> 4;

    const int ul = tid & 127;
    const int th = (tid >> 7) * 16;

    f32x4 acc[4][4] = {};

    for (int k0 = 0; k0 < TENC; k0 += 32) {
        float av[16], bv[16];
#pragma unroll
        for (int i = 0; i < 4; ++i) {
            const int t = k0 + th + i * 4;
#pragma unroll
            for (int j = 0; j < 4; ++j) {
                av[i * 4 + j] = S[(size_t)(t + j) * TDEC + m0 + ul];
                bv[i * 4 + j] = E[(size_t)(t + j) * DIM + n0 + ul];
            }
        }
        __syncthreads();
#pragma unroll
        for (int i = 0; i < 4; ++i) {
            const int tt = th + i * 4;
            wr4(&Ah[ul * G2_LD + tt], &Al[ul * G2_LD + tt], &av[i * 4]);
            wr4(&Bh[ul * G2_LD + tt], &Bl[ul * G2_LD + tt], &bv[i * 4]);
        }
        __syncthreads();

        short8 ah[4], al[4], bh[4], bl[4];
#pragma unroll
        for (int i = 0; i < 4; ++i) {
            ah[i] = frag8B(&Ah[(wm + i * 16 + lr) * G2_LD + q * 8]);
            al[i] = frag8B(&Al[(wm + i * 16 + lr) * G2_LD + q * 8]);
            bh[i] = frag8B(&Bh[(wn + i * 16 + lr) * G2_LD + q * 8]);
            bl[i] = frag8B(&Bl[(wn + i * 16 + lr) * G2_LD + q * 8]);
        }
#pragma unroll
        for (int i = 0; i < 4; ++i)
#pragma unroll
            for (int j = 0; j < 4; ++j) {
                acc[i][j] = __builtin_amdgcn_mfma_f32_16x16x32_bf16(ah[i], bh[j], acc[i][j], 0, 0, 0);
                acc[i][j] = __builtin_amdgcn_mfma_f32_16x16x32_bf16(ah[i], bl[j], acc[i][j], 0, 0, 0);
                acc[i][j] = __builtin_amdgcn_mfma_f32_16x16x32_bf16(al[i], bh[j], acc[i][j], 0, 0, 0);
            }
    }

#pragma unroll
    for (int i = 0; i < 4; ++i)
#pragma unroll
        for (int rr = 0; rr < 4; ++rr) {
            const int u = m0 + wm + i * 16 + q * 4 + rr;
#pragma unroll
            for (int j = 0; j < 4; ++j) {
                const int d = n0 + wn + j * 16 + lr;
                C[(size_t)u * DIM + d] = acc[i][j][rr];
            }
        }
}

// ===========================================================================
extern "C" void kernel_launch(void* const* d_in, const int* in_sizes, int n_in,
                              void* d_out, int out_size, void* d_ws, size_t ws_size,
                              hipStream_t stream)
{
    const float* enc      = (const float*)d_in[0];
    const int*   enc_mask = (const int*)  d_in[1];
    const float* dec      = (const float*)d_in[2];

    float* context = (float*)d_out;                        // B*TDEC*DIM
    float* scores  = context + (size_t)BATCH * TDEC * DIM; // B*TENC*TDEC

    // workspace layout (bytes).
    // pm/ps overlay scoresT (consumed by colstat2 before norm writes scoresT).
    // p0/p1 overlay encH/encL (dead after gemm1; each partial is 16 MiB).
    const size_t OFF_ENC_H = 0;
    const size_t OFF_ENC_L = 33554432;
    const size_t OFF_DEC_H = 67108864;
    const size_t OFF_DEC_L = 75497472;
    const size_t OFF_ENC_T = 83886080;
    const size_t OFF_SCO_T = 117440512;
    const size_t OFF_PM    = OFF_SCO_T;
    const size_t OFF_PS    = OFF_SCO_T + 262144;
    const size_t OFF_COL_M = 134217728;
    const size_t OFF_COL_I = 134234112;
    const size_t WS_NEED   = 134381568;

    if (ws_size >= WS_NEED) {
        char* w = (char*)d_ws;
        ushort_t* encH    = (ushort_t*)(w + OFF_ENC_H);
        ushort_t* encL    = (ushort_t*)(w + OFF_ENC_L);
        ushort_t* decH    = (ushort_t*)(w + OFF_DEC_H);
        ushort_t* decL    = (ushort_t*)(w + OFF_DEC_L);
        ushort_t* encT    = (ushort_t*)(w + OFF_ENC_T);
        ushort_t* scoresT = (ushort_t*)(w + OFF_SCO_T);
        float*    pm      = (float*)(w + OFF_PM);
        float*    ps      = (float*)(w + OFF_PS);
        float*    colM    = (float*)(w + OFF_COL_M);
        float*    colI    = (float*)(w + OFF_COL_I);
        float*    part0   = (float*)(w + OFF_ENC_H);   // overlay, 16 MiB
        float*    part1   = (float*)(w + OFF_ENC_L);   // overlay, 16 MiB

        prep_enc<<<dim3(DIM / 64, TENC / 64, BATCH), 256, 0, stream>>>(
            enc, encH, encL, encT);
        prep_dec<<<dim3(DIM / 64, TDEC / 64, BATCH), 256, 0, stream>>>(
            dec, decH, decL);

        gemm1_lds<<<dim3(TDEC / 128, TENC / 128, BATCH), 256, 0, stream>>>(
            encH, encL, decH, decL, enc_mask, scores, pm, ps);

        colstat2<<<16, 256, 0, stream>>>(pm, ps, colM, colI);

        norm_kernel<<<dim3(TENC / 64, TDEC / 64, BATCH), 256, 0, stream>>>(
            scores, colM, colI, scoresT);

        gemm2_lds<<<dim3(DIM / 128, TDEC / 128, BATCH * 2), 256, 0, stream>>>(
            scoresT, encT, part0, part1);

        reduce_ctx<<<4096, 256, 0, stream>>>(part0, part1, context);
    } else {
        gemm1_mfma<<<dim3(TDEC / 128, TENC / 128, BATCH), 256, 0, stream>>>(
            enc, dec, enc_mask, scores);
        softmax_kernel<<<dim3(TDEC / 16, BATCH), 256, 0, stream>>>(scores);
        gemm2_mfma<<<dim3(DIM / 128, TDEC / 128, BATCH), 256, 0, stream>>>(
            scores, enc, context);
    }
}